// Round 17
// baseline (4643.586 us; speedup 1.0000x reference)
//
#include <hip/hip_runtime.h>
#include <hip/hip_bf16.h>

#define R_TOT  8192      // B*S
#define DIM    768       // D
#define FDICT  32768
#define TOPK   128
#define LN_EPS 1e-5f
#define BAND_M 0.12f
#define BAND_CAP 192
#define ZPRE   2.25f
#define CCAP   16        // candidates per (row, 256-col tile)
#define NTILE  128       // FDICT/256

using f32x4  = __attribute__((ext_vector_type(4))) float;
using short8 = __attribute__((ext_vector_type(8))) short;

__device__ inline short f2bf(float f) {
    __hip_bfloat16 h = __float2bfloat16(f);
    return *reinterpret_cast<short*>(&h);
}
__device__ inline float bf2f(short s) {
    return __uint_as_float(((unsigned)(unsigned short)s) << 16);
}
__device__ inline void load_lds16(const void* g, void* l) {
    __builtin_amdgcn_global_load_lds(
        (const __attribute__((address_space(1))) unsigned int*)g,
        (__attribute__((address_space(3))) unsigned int*)l, 16, 0, 0);
}
#define LGKM0() do { asm volatile("s_waitcnt lgkmcnt(0)" ::: "memory"); \
                     __builtin_amdgcn_sched_barrier(0); } while (0)
#define BAR()   __builtin_amdgcn_s_barrier()

// ---------------- K0: fused prep: conv(x), conv(Wenc), transpose(Wdec), gbinfo --
__global__ __launch_bounds__(256) void prep_fused(
    const float* __restrict__ x, const float* __restrict__ Wenc,
    const float* __restrict__ Wdec, const float* __restrict__ gamma,
    const float* __restrict__ beta, unsigned short* __restrict__ Xb,
    unsigned short* __restrict__ Wb, unsigned short* __restrict__ WdTb,
    float* __restrict__ gbinfo)
{
    __shared__ float tile[32][33];
    const int b = blockIdx.x;
    const int t = threadIdx.x;

    if (b < 1536) {                       // conv x -> Xb (bf16)
        const int n8 = R_TOT * DIM / 8;
        for (int g = b * 256 + t; g < n8; g += 1536 * 256) {
            const float4 a = ((const float4*)x)[g * 2];
            const float4 c = ((const float4*)x)[g * 2 + 1];
            short8 v;
            v[0] = f2bf(a.x); v[1] = f2bf(a.y); v[2] = f2bf(a.z); v[3] = f2bf(a.w);
            v[4] = f2bf(c.x); v[5] = f2bf(c.y); v[6] = f2bf(c.z); v[7] = f2bf(c.w);
            ((short8*)Xb)[g] = v;
        }
    } else if (b < 3584) {                // conv Wenc -> Wb (bf16)
        const int n8 = FDICT * DIM / 8;
        for (int g = (b - 1536) * 256 + t; g < n8; g += 2048 * 256) {
            const float4 a = ((const float4*)Wenc)[g * 2];
            const float4 c = ((const float4*)Wenc)[g * 2 + 1];
            short8 v;
            v[0] = f2bf(a.x); v[1] = f2bf(a.y); v[2] = f2bf(a.z); v[3] = f2bf(a.w);
            v[4] = f2bf(c.x); v[5] = f2bf(c.y); v[6] = f2bf(c.z); v[7] = f2bf(c.w);
            ((short8*)Wb)[g] = v;
        }
    } else if (b < 3584 + 24576) {        // transpose Wdec -> WdTb (bf16)
        const int b2 = b - 3584;
        const int fx = (b2 & 1023) * 32;
        const int dy = (b2 >> 10) * 32;
        const int tx = t & 31;
        const int ty = t >> 5;
        for (int i = ty; i < 32; i += 8)
            tile[i][tx] = Wdec[(size_t)(dy + i) * FDICT + fx + tx];
        __syncthreads();
        for (int i = ty; i < 32; i += 8)
            WdTb[(size_t)(fx + i) * DIM + dy + tx] = (unsigned short)f2bf(tile[tx][i]);
    } else {                              // gamma/beta info
        float* rr = &tile[0][0];
        const int w = t >> 6;
        float gmn = 1e30f, gmx = -1e30f, bmn = 1e30f, bmx = -1e30f;
        for (int i = t; i < FDICT / 4; i += 256) {
            const float4 g4 = ((const float4*)gamma)[i];
            const float4 b4 = ((const float4*)beta)[i];
            gmn = fminf(gmn, fminf(fminf(g4.x, g4.y), fminf(g4.z, g4.w)));
            gmx = fmaxf(gmx, fmaxf(fmaxf(g4.x, g4.y), fmaxf(g4.z, g4.w)));
            bmn = fminf(bmn, fminf(fminf(b4.x, b4.y), fminf(b4.z, b4.w)));
            bmx = fmaxf(bmx, fmaxf(fmaxf(b4.x, b4.y), fmaxf(b4.z, b4.w)));
        }
#pragma unroll
        for (int o = 32; o > 0; o >>= 1) {
            gmn = fminf(gmn, __shfl_down(gmn, o, 64));
            gmx = fmaxf(gmx, __shfl_down(gmx, o, 64));
            bmn = fminf(bmn, __shfl_down(bmn, o, 64));
            bmx = fmaxf(bmx, __shfl_down(bmx, o, 64));
        }
        if ((t & 63) == 0) {
            rr[w * 4 + 0] = gmn; rr[w * 4 + 1] = gmx;
            rr[w * 4 + 2] = bmn; rr[w * 4 + 3] = bmx;
        }
        __syncthreads();
        if (t == 0) {
            float a = rr[0], b_ = rr[1], c = rr[2], d = rr[3];
            for (int i = 1; i < 4; ++i) {
                a = fminf(a, rr[i * 4 + 0]); b_ = fmaxf(b_, rr[i * 4 + 1]);
                c = fminf(c, rr[i * 4 + 2]); d = fmaxf(d, rr[i * 4 + 3]);
            }
            gbinfo[0] = fmaxf(fabsf(a), fabsf(b_));
            gbinfo[1] = fmaxf(fabsf(c), fabsf(d));
            gbinfo[2] = (a == b_ && c == d) ? 1.f : 0.f;
            gbinfo[3] = b_;
            gbinfo[4] = d;
        }
    }
}

// ---------------- K1: encoder GEMM — 256x256 tile, 8-wave, 4-phase/K-tile -------
// Big path (candv!=null): NO Zb write; epilogue emits per-(row,tile) partial
// stats (deterministic) + candidates z > ZPRE (cap 16, overflow flagged via
// count).  Small path (candv==null): classic Cs/Zb bf16 store.
#define READ_A(P)                                                              \
    af00 = *(const short8*)&Sb[abase + (2*(P))*1024 + sw0];                    \
    af01 = *(const short8*)&Sb[abase + (2*(P))*1024 + sw1];                    \
    af10 = *(const short8*)&Sb[abase + (2*(P)+1)*1024 + sw0];                  \
    af11 = *(const short8*)&Sb[abase + (2*(P)+1)*1024 + sw1];

#define DO_MFMA(P)                                                             \
    __builtin_amdgcn_s_setprio(1);                                             \
    _Pragma("unroll")                                                          \
    for (int n = 0; n < 4; ++n) {                                              \
        acc[2*(P)][n]   = __builtin_amdgcn_mfma_f32_16x16x32_bf16(af00, bf0[n], acc[2*(P)][n],   0,0,0); \
        acc[2*(P)][n]   = __builtin_amdgcn_mfma_f32_16x16x32_bf16(af01, bf1[n], acc[2*(P)][n],   0,0,0); \
        acc[2*(P)+1][n] = __builtin_amdgcn_mfma_f32_16x16x32_bf16(af10, bf0[n], acc[2*(P)+1][n], 0,0,0); \
        acc[2*(P)+1][n] = __builtin_amdgcn_mfma_f32_16x16x32_bf16(af11, bf1[n], acc[2*(P)+1][n], 0,0,0); \
    }                                                                          \
    __builtin_amdgcn_s_setprio(0);

__global__ __launch_bounds__(512, 2) void enc_gemm(
    const unsigned short* __restrict__ Xb, const unsigned short* __restrict__ Wb,
    const float* __restrict__ benc, unsigned short* __restrict__ Zb,
    float* __restrict__ featZero, float2* __restrict__ candv,
    int* __restrict__ cntg, float2* __restrict__ partials)
{
    __shared__ __align__(16) unsigned short S[65536];   // 128 KiB

    const int t = threadIdx.x;
    const int w = t >> 6, l = t & 63;

    const int cpx = (int)gridDim.x >> 3;
    const int swz = ((int)blockIdx.x & 7) * cpx + ((int)blockIdx.x >> 3);
    const long bm = (long)(swz >> 7) * 256;     // bm-major
    const long bn = (long)(swz & 127) * 256;

    const int wm = w >> 2, wn = w & 3;
    const int lrow = l & 15, l4 = l >> 4;

    const int sw0 = ((l4     ) ^ (lrow & 7)) * 8;
    const int sw1 = ((4 + l4 ) ^ (lrow & 7)) * 8;
    const int abase = wm * 8192 + lrow * 64;
    const int bbase = 16384 + wn * 4096 + lrow * 64;

    const int rh0 = w * 16 + (l >> 3);
    const int rh1 = rh0 + 8;
    const int gsl = ((l & 7) ^ (l >> 3)) * 8;
    const unsigned short* pA00 = Xb + (bm +       rh0) * DIM + gsl;
    const unsigned short* pA01 = Xb + (bm +       rh1) * DIM + gsl;
    const unsigned short* pA10 = Xb + (bm + 128 + rh0) * DIM + gsl;
    const unsigned short* pA11 = Xb + (bm + 128 + rh1) * DIM + gsl;
    const unsigned short* pB00 = Wb + (bn +       rh0) * DIM + gsl;
    const unsigned short* pB01 = Wb + (bn +       rh1) * DIM + gsl;
    const unsigned short* pB10 = Wb + (bn + 128 + rh0) * DIM + gsl;
    const unsigned short* pB11 = Wb + (bn + 128 + rh1) * DIM + gsl;
    const int d00 = w * 1024;
    const int d01 = w * 1024 + 512;

    f32x4* zp = featZero ? ((f32x4*)featZero + (size_t)blockIdx.x * 16384) : nullptr;
    const f32x4 z4 = (f32x4){0.f, 0.f, 0.f, 0.f};

    f32x4 acc[8][4];
#pragma unroll
    for (int m = 0; m < 8; ++m)
#pragma unroll
        for (int n = 0; n < 4; ++n) acc[m][n] = (f32x4){0.f, 0.f, 0.f, 0.f};

    load_lds16(pA00, S + d00);
    load_lds16(pA01, S + d01);
    load_lds16(pA10, S + 8192 + d00);
    load_lds16(pA11, S + 8192 + d01);
    load_lds16(pB00, S + 16384 + d00);
    load_lds16(pB01, S + 16384 + d01);
    load_lds16(pB10, S + 16384 + 8192 + d00);
    load_lds16(pB11, S + 16384 + 8192 + d01);
    pA00 += 64; pA01 += 64; pA10 += 64; pA11 += 64;
    pB00 += 64; pB01 += 64; pB10 += 64; pB11 += 64;

    short8 bf0[4], bf1[4];
    short8 af00, af01, af10, af11;

#pragma unroll 1
    for (int kt = 0; kt < 12; ++kt) {
        const unsigned short* Sb = S + (kt & 1) * 32768;
        unsigned short*       Sn = S + ((kt & 1) ^ 1) * 32768;

        if (kt < 11) {
            load_lds16(pA00, Sn + d00);
            load_lds16(pA01, Sn + d01);
            load_lds16(pA10, Sn + 8192 + d00);
            load_lds16(pA11, Sn + 8192 + d01);
            asm volatile("s_waitcnt vmcnt(4)" ::: "memory");
        } else {
            asm volatile("s_waitcnt vmcnt(0)" ::: "memory");
        }
        __builtin_amdgcn_s_barrier();

        if (zp) {
            const int base = kt * 3;
#pragma unroll
            for (int i = 0; i < 3; ++i) {
                const int s = base + i;
                if (s < 32) __builtin_nontemporal_store(z4, zp + t + s * 512);
            }
        }

#pragma unroll
        for (int n = 0; n < 4; ++n) {
            bf0[n] = *(const short8*)&Sb[bbase + n * 1024 + sw0];
            bf1[n] = *(const short8*)&Sb[bbase + n * 1024 + sw1];
        }
        READ_A(0)
        DO_MFMA(0)
        asm volatile("" ::: "memory");
        __builtin_amdgcn_s_barrier();

        READ_A(1)
        if (kt < 11) {
            load_lds16(pB00, Sn + 16384 + d00);
            load_lds16(pB01, Sn + 16384 + d01);
            load_lds16(pB10, Sn + 16384 + 8192 + d00);
            load_lds16(pB11, Sn + 16384 + 8192 + d01);
        }
        asm volatile("" ::: "memory");
        __builtin_amdgcn_s_barrier();
        DO_MFMA(1)
        asm volatile("" ::: "memory");
        __builtin_amdgcn_s_barrier();

        READ_A(2)
        asm volatile("" ::: "memory");
        __builtin_amdgcn_s_barrier();
        DO_MFMA(2)
        asm volatile("" ::: "memory");
        __builtin_amdgcn_s_barrier();

        READ_A(3)
        asm volatile("" ::: "memory");
        __builtin_amdgcn_s_barrier();
        DO_MFMA(3)
        asm volatile("" ::: "memory");
        __builtin_amdgcn_s_barrier();

        pA00 += 64; pA01 += 64; pA10 += 64; pA11 += 64;
        pB00 += 64; pB01 += 64; pB10 += 64; pB11 += 64;
    }

    __syncthreads();
    float bias[4];
#pragma unroll
    for (int n = 0; n < 4; ++n) bias[n] = benc[bn + wn * 64 + n * 16 + lrow];

    if (candv == nullptr) {
        // ---- small path: Cs overlay + bf16 Zb store ----
        unsigned short* Cs = S;
#pragma unroll
        for (int m = 0; m < 8; ++m)
#pragma unroll
            for (int n = 0; n < 4; ++n)
#pragma unroll
                for (int q = 0; q < 4; ++q)
                    Cs[(wm * 128 + m * 16 + l4 * 4 + q) * 256 + wn * 64 + n * 16 + lrow] =
                        (unsigned short)f2bf(acc[m][n][q] + bias[n]);
        __syncthreads();
#pragma unroll
        for (int it = 0; it < 16; ++it) {
            const int g = t + it * 512;
            const int row = g >> 5;
            const int c8 = (g & 31) * 8;
            const short8 v = *(const short8*)&Cs[row * 256 + c8];
            __builtin_nontemporal_store(v, (short8*)&Zb[(bm + row) * FDICT + bn + c8]);
        }
        return;
    }

    // ---- big path: per-row partial stats + candidate extraction ----
    float* ps   = (float*)S;             // [256][4]
    float* qs   = ps + 1024;             // [256][4]
    int*   cntl = (int*)(qs + 1024);     // [256]
    float2* cb  = (float2*)(cntl + 256); // [256][16]  (32 KB)

    if (t < 256) cntl[t] = 0;
    __syncthreads();

#pragma unroll
    for (int m = 0; m < 8; ++m) {
#pragma unroll
        for (int q = 0; q < 4; ++q) {
            const int rl = wm * 128 + m * 16 + l4 * 4 + q;
            float s4 = 0.f, q4 = 0.f;
#pragma unroll
            for (int n = 0; n < 4; ++n) {
                const float z = acc[m][n][q] + bias[n];
                s4 += z; q4 += z * z;
                if (z > ZPRE) {
                    const int slot = atomicAdd(&cntl[rl], 1);
                    if (slot < CCAP) {
                        float2 e;
                        e.x = z;
                        e.y = __int_as_float((int)(bn + wn * 64 + n * 16 + lrow));
                        cb[rl * CCAP + slot] = e;
                    }
                }
            }
#pragma unroll
            for (int o = 1; o < 16; o <<= 1) {
                s4 += __shfl_xor(s4, o, 64);
                q4 += __shfl_xor(q4, o, 64);
            }
            if (lrow == 0) { ps[rl * 4 + wn] = s4; qs[rl * 4 + wn] = q4; }
        }
    }
    __syncthreads();
    if (t < 256) {
        const int bnt = (int)(bn >> 8);
        const size_t gi = (((size_t)(bm + t)) << 7) + bnt;
        float2 p;
        p.x = ps[t * 4 + 0] + ps[t * 4 + 1] + ps[t * 4 + 2] + ps[t * 4 + 3];
        p.y = qs[t * 4 + 0] + qs[t * 4 + 1] + qs[t * 4 + 2] + qs[t * 4 + 3];
        partials[gi] = p;
        const int c = cntl[t];
        cntg[gi] = c;
        const int cc = c > CCAP ? CCAP : c;
        float2* dst = candv + gi * CCAP;
        for (int j = 0; j < cc; ++j) dst[j] = cb[t * CCAP + j];
    }
}

// ---------------- K2: candidate-based topk (fast path) ---------------------------
// One block (256 thr) per row.  All correctness conditions checked at runtime;
// any failure -> flags[r]=1 -> topk_fallback recomputes the row exactly.
__global__ __launch_bounds__(256) void topk_cand(
    const float2* __restrict__ partials, const int* __restrict__ cntg,
    const float2* __restrict__ candv, const float* __restrict__ gbinfo,
    int* __restrict__ flags, int* __restrict__ sel_idx, float* __restrict__ sel_val,
    int* __restrict__ band_idx, int* __restrict__ cdef, int* __restrict__ nband,
    float* __restrict__ muarr, float* __restrict__ sinvarr)
{
    __shared__ float ps[128], qs[128];
    __shared__ int   cnts[128], offs[129];
    __shared__ float2 cb[2048];          // 16 KB
    __shared__ int   bad;
    __shared__ unsigned cacc[4];
    __shared__ unsigned scomp[2];

    const int t = threadIdx.x;
    const long r = blockIdx.x;
    const float g0 = gbinfo[3], b0 = gbinfo[4];
    const bool uniform = (gbinfo[2] != 0.f) && (g0 > 0.f) && (g0 <= 2.f);

    if (t == 0) { bad = 0; scomp[0] = 0u; scomp[1] = 0u; }
    if (t < 4) cacc[t] = 0u;
    __syncthreads();
    if (!uniform) { if (t == 0) flags[r] = 1; return; }

    if (t < 128) {
        const float2 p = partials[r * NTILE + t];
        ps[t] = p.x; qs[t] = p.y;
        const int c = cntg[r * NTILE + t];
        cnts[t] = c;
        if (c > CCAP) atomicOr(&bad, 1);
    }
    __syncthreads();
    for (int s = 64; s > 0; s >>= 1) {
        if (t < s) { ps[t] += ps[t + s]; qs[t] += qs[t + s]; }
        __syncthreads();
    }
    const float mu = ps[0] / (float)FDICT;
    float var = qs[0] / (float)FDICT - mu * mu;
    if (var < 0.f) var = 0.f;
    const float sinv = 1.f / sqrtf(var + LN_EPS);

    if (t == 0) {
        int a = 0;
        for (int i = 0; i < 128; ++i) {
            offs[i] = a;
            a += (cnts[i] > CCAP ? CCAP : cnts[i]);
        }
        offs[128] = a;
        if (a > 2048 || a < TOPK) bad = 1;
    }
    __syncthreads();
    if (bad) { if (t == 0) flags[r] = 1; return; }
    const int NC = offs[128];
    if (t < 128) {
        const int c = cnts[t] > CCAP ? CCAP : cnts[t];
        const float2* src = candv + ((size_t)(r * NTILE + t)) * CCAP;
        for (int j = 0; j < c; ++j) cb[offs[t] + j] = src[j];
    }
    __syncthreads();

    const float gs = sinv * g0;
    for (int i = t; i < NC; i += 256)
        cb[i].x = fmaxf(fmaf(cb[i].x - mu, gs, b0), 0.f);
    __syncthreads();

    const float a_limit = fmaf(ZPRE - mu, gs, b0);
    const float Vh = fmaf(2.6601f, g0, b0);
    const float h  = 0.25f * g0;
    float lo = Vh - h, hi = Vh + h;
    if (lo <= a_limit) { if (t == 0) flags[r] = 1; return; }

    unsigned pc = 0;
    for (int i = t; i < NC; i += 256) {
        const float a = cb[i].x;
        pc += (a > lo) ? 1u : 0u;
        pc += (a > hi) ? 0x10000u : 0u;
    }
#pragma unroll
    for (int o = 32; o > 0; o >>= 1) pc += __shfl_down(pc, o, 64);
    if ((t & 63) == 0) atomicAdd(&cacc[0], pc);
    __syncthreads();
    const unsigned clo = cacc[0] & 0xFFFFu, chi = cacc[0] >> 16;
    if (clo < TOPK || chi >= TOPK) { if (t == 0) flags[r] = 1; return; }

#pragma unroll 1
    for (int it = 1; it <= 3; ++it) {
        const float thr = 0.5f * (lo + hi);
        unsigned cnt2 = 0;
        for (int i = t; i < NC; i += 256) cnt2 += (cb[i].x > thr) ? 1u : 0u;
#pragma unroll
        for (int o = 32; o > 0; o >>= 1) cnt2 += __shfl_down(cnt2, o, 64);
        if ((t & 63) == 0) atomicAdd(&cacc[it], cnt2);
        __syncthreads();
        if (cacc[it] >= TOPK) lo = thr; else hi = thr;
    }
    const float Tf = 0.5f * (lo + hi);
    const float thi = Tf + BAND_M, tlo = Tf - BAND_M;
    if (tlo <= a_limit) { if (t == 0) flags[r] = 1; return; }

    for (int i = t; i < NC; i += 256) {
        const float a = cb[i].x;
        if (a > thi) {
            const unsigned s = atomicAdd(&scomp[0], 1u);
            sel_idx[r * TOPK + s] = __float_as_int(cb[i].y);
            sel_val[r * TOPK + s] = a;
        } else if (a >= tlo) {
            const unsigned s = atomicAdd(&scomp[1], 1u);
            if (s < BAND_CAP) band_idx[r * BAND_CAP + s] = __float_as_int(cb[i].y);
        }
    }
    __syncthreads();
    if (t == 0) {
        if (scomp[1] > BAND_CAP) { flags[r] = 1; }
        else {
            cdef[r] = (int)scomp[0];
            nband[r] = (int)scomp[1];
            muarr[r] = mu; sinvarr[r] = sinv;
            flags[r] = 0;
        }
    }
}

// ---------------- K2f: fallback — exact row recompute + full bisection -----------
__global__ __launch_bounds__(1024) void topk_fallback(
    const float* __restrict__ X, const float* __restrict__ Wenc,
    const float* __restrict__ benc, const float* __restrict__ gamma,
    const float* __restrict__ beta, const int* __restrict__ flags,
    int* __restrict__ sel_idx, float* __restrict__ sel_val,
    int* __restrict__ band_idx, int* __restrict__ cdef, int* __restrict__ nband,
    float* __restrict__ muarr, float* __restrict__ sinvarr)
{
    __shared__ float zs[FDICT];          // 128 KB
    __shared__ float redf[32];
    __shared__ unsigned cacc[16];
    __shared__ unsigned scomp[2];
    const long r = blockIdx.x;
    if (flags[r] == 0) return;
    const int t = threadIdx.x;
    const int w = t >> 6;

    // fp32 GEMV: z[col] = <x_r, Wenc[col,:]> + benc[col]
#pragma unroll 1
    for (int c = 0; c < 32; ++c) {
        const int col = c * 1024 + t;
        const float* wr = Wenc + (size_t)col * DIM;
        float s = 0.f;
        for (int k = 0; k < DIM; ++k) s = fmaf(X[r * DIM + k], wr[k], s);
        zs[col] = s + benc[col];
    }
    __syncthreads();
    if (t < 16) cacc[t] = 0u;
    if (t == 16) { scomp[0] = 0u; scomp[1] = 0u; }

    float sum = 0.f, ssq = 0.f;
    for (int i = t; i < FDICT; i += 1024) { const float z = zs[i]; sum += z; ssq += z * z; }
#pragma unroll
    for (int o = 32; o > 0; o >>= 1) {
        sum += __shfl_down(sum, o, 64);
        ssq += __shfl_down(ssq, o, 64);
    }
    if ((t & 63) == 0) { redf[w] = sum; redf[16 + w] = ssq; }
    __syncthreads();
    float s_ = 0.f, q_ = 0.f;
#pragma unroll
    for (int i = 0; i < 16; ++i) { s_ += redf[i]; q_ += redf[16 + i]; }
    const float mu = s_ / (float)FDICT;
    float var = q_ / (float)FDICT - mu * mu;
    if (var < 0.f) var = 0.f;
    const float sinv = 1.f / sqrtf(var + LN_EPS);
    __syncthreads();

    // normalize in place + vmax
    float vmax = 0.f;
    for (int i = t; i < FDICT; i += 1024) {
        const float a = fmaxf(fmaf((zs[i] - mu) * sinv, gamma[i], beta[i]), 0.f);
        zs[i] = a;
        vmax = fmaxf(vmax, a);
    }
#pragma unroll
    for (int o = 32; o > 0; o >>= 1) vmax = fmaxf(vmax, __shfl_down(vmax, o, 64));
    if ((t & 63) == 0) redf[w] = vmax;
    __syncthreads();
    float mx = 0.f;
#pragma unroll
    for (int i = 0; i < 16; ++i) mx = fmaxf(mx, redf[i]);

    float lo = 0.f, hi = mx + 1e-6f;
#pragma unroll 1
    for (int it = 0; it < 12; ++it) {
        const float thr = 0.5f * (lo + hi);
        unsigned cnt = 0;
        for (int i = t; i < FDICT; i += 1024) cnt += (zs[i] > thr) ? 1u : 0u;
#pragma unroll
        for (int o = 32; o > 0; o >>= 1) cnt += __shfl_down(cnt, o, 64);
        if ((t & 63) == 0) atomicAdd(&cacc[it], cnt);
        __syncthreads();
        if (cacc[it] >= TOPK) lo = thr; else hi = thr;
    }
    const float Tf = 0.5f * (lo + hi);
    const float thi = Tf + BAND_M, tlo = Tf - BAND_M;

    for (int i = t; i < FDICT; i += 1024) {
        const float a = zs[i];
        if (a > thi) {
            const unsigned s = atomicAdd(&scomp[0], 1u);
            sel_idx[r * TOPK + s] = i;
            sel_val[r * TOPK + s] = a;
        } else if (a >= tlo) {
            const unsigned s = atomicAdd(&scomp[1], 1u);
            if (s < BAND_CAP) band_idx[r * BAND_CAP + s] = i;
        }
    }
    __syncthreads();
    if (t == 0) {
        cdef[r] = (int)scomp[0];
        int nb = (int)scomp[1]; if (nb > BAND_CAP) nb = BAND_CAP;
        nband[r] = nb;
        muarr[r] = mu; sinvarr[r] = sinv;
    }
}

// ---------------- K2s: small-ws path topk (r16-proven, Zb pipelined) -------------
__global__ __launch_bounds__(1024) void topk_zb(
    const unsigned short* __restrict__ Zb, const float* __restrict__ gamma,
    const float* __restrict__ beta, const float* __restrict__ gbinfo,
    int* __restrict__ sel_idx, float* __restrict__ sel_val,
    int* __restrict__ band_idx, int* __restrict__ cdef, int* __restrict__ nband,
    float* __restrict__ muarr, float* __restrict__ sinvarr)
{
    __shared__ __align__(16) unsigned short rowbuf[FDICT];
    __shared__ float    redf[32];
    __shared__ unsigned cacc[16];
    __shared__ unsigned scomp[2];

    const int t = threadIdx.x;
    const int w = t >> 6;
    const long r0 = (long)blockIdx.x * 4;

    const float g0 = gbinfo[3], b0 = gbinfo[4];
    const bool uniform = (gbinfo[2] != 0.f) && (g0 > 0.f) && (g0 <= 2.f);

    const int lbase = w * 512;
    const int goff  = w * 512 + (t & 63) * 8;

    {
        const unsigned short* src = Zb + r0 * FDICT + goff;
#pragma unroll
        for (int q = 0; q < 4; ++q)
            load_lds16(src + q * 8192, rowbuf + lbase + q * 8192);
    }

#pragma unroll 1
    for (int i = 0; i < 4; ++i) {
        const long r = r0 + i;
        asm volatile("s_waitcnt vmcnt(0)" ::: "memory");
        BAR();

        unsigned u[32];
        float sum = 0.f, sumsq = 0.f;
#pragma unroll
        for (int q = 0; q < 4; ++q) {
            const short8 v = *(const short8*)&rowbuf[q * 8192 + t * 8];
#pragma unroll
            for (int j = 0; j < 8; ++j) {
                const float f = bf2f(v[j]);
                u[q * 8 + j] = __float_as_uint(f);
                sum += f; sumsq += f * f;
            }
        }
        LGKM0();
        BAR();
        if (t < 16) cacc[t] = 0u;
        if (t == 16) { scomp[0] = 0u; scomp[1] = 0u; }
        if (i < 3) {
            const unsigned short* src = Zb + (r + 1) * FDICT + goff;
#pragma unroll
            for (int q = 0; q < 4; ++q)
                load_lds16(src + q * 8192, rowbuf + lbase + q * 8192);
        }

#pragma unroll
        for (int o = 32; o > 0; o >>= 1) {
            sum   += __shfl_down(sum, o, 64);
            sumsq += __shfl_down(sumsq, o, 64);
        }
        if ((t & 63) == 0) { redf[w] = sum; redf[16 + w] = sumsq; }
        LGKM0();
        BAR();
        float s_ = 0.f, sq_ = 0.f;
#pragma unroll
        for (int k = 0; k < 16; ++k) { s_ += redf[k]; sq_ += redf[16 + k]; }
        const float mu = s_ / (float)FDICT;
        float var = sq_ / (float)FDICT - mu * mu;
        if (var < 0.f) var = 0.f;
        const float sinv = 1.f / sqrtf(var + LN_EPS);

        if (uniform) {
            const float gs = sinv * g0;
#pragma unroll
            for (int k = 0; k < 32; ++k)
                u[k] = __float_as_uint(fmaxf(
                    fmaf(__uint_as_float(u[k]) - mu, gs, b0), 0.f));
        } else {
#pragma unroll
            for (int q = 0; q < 4; ++q) {
                const size_t base = (size_t)(q * 1024 + t) * 8;
                const float4 g4a = *(const float4*)(gamma + base);
                const float4 g4b = *(const float4*)(gamma + base + 4);
                const float4 b4a = *(const float4*)(beta + base);
                const float4 b4b = *(const float4*)(beta + base + 4);
                const float gsv[8] = {g4a.x, g4a.y, g4a.z, g4a.w, g4b.x, g4b.y, g4b.z, g4b.w};
                const float bsv[8] = {b4a.x, b4a.y, b4a.z, b4a.w, b4b.x, b4b.y, b4b.z, b4b.w};
#pragma unroll
                for (int j = 0; j < 8; ++j) {
                    const int k = q * 8 + j;
                    u[k] = __float_as_uint(fmaxf(
                        fmaf((__uint_as_float(u[k]) - mu) * sinv, gsv[j], bsv[j]), 0.f));
                }
            }
        }

        float Tf = 0.f;
        bool got = false;
        int nextacc = 0;
        if (uniform) {
            const float Vh = fmaf(2.6601f, g0, b0);
            const float h  = 0.25f * g0;
            float lo = Vh - h, hi = Vh + h;
            unsigned pc = 0;
#pragma unroll
            for (int k = 0; k < 32; ++k) {
                const float a = __uint_as_float(u[k]);
                pc += (a > lo) ? 1u : 0u;
                pc += (a > hi) ? 0x10000u : 0u;
            }
#pragma unroll
            for (int o = 32; o > 0; o >>= 1) pc += __shfl_down(pc, o, 64);
            if ((t & 63) == 0) atomicAdd(&cacc[0], pc);
            LGKM0();
            BAR();
            const unsigned clo = cacc[0] & 0xFFFFu, chi = cacc[0] >> 16;
            if (clo >= TOPK && chi < TOPK) {
#pragma unroll 1
                for (int it = 1; it <= 3; ++it) {
                    const float thr = 0.5f * (lo + hi);
                    unsigned cnt = 0;
#pragma unroll
                    for (int k = 0; k < 32; ++k)
                        cnt += (__uint_as_float(u[k]) > thr) ? 1u : 0u;
#pragma unroll
                    for (int o = 32; o > 0; o >>= 1) cnt += __shfl_down(cnt, o, 64);
                    if ((t & 63) == 0) atomicAdd(&cacc[it], cnt);
                    LGKM0();
                    BAR();
                    if (cacc[it] >= TOPK) lo = thr; else hi = thr;
                }
                Tf = 0.5f * (lo + hi);
                got = true;
            }
            nextacc = 4;
        }
        if (!got) {
            float vmax = 0.f;
#pragma unroll
            for (int k = 0; k < 32; ++k) vmax = fmaxf(vmax, __uint_as_float(u[k]));
#pragma unroll
            for (int o = 32; o > 0; o >>= 1) vmax = fmaxf(vmax, __shfl_down(vmax, o, 64));
            if ((t & 63) == 0) redf[w] = vmax;
            LGKM0();
            BAR();
            float mx = 0.f;
#pragma unroll
            for (int k = 0; k < 16; ++k) mx = fmaxf(mx, redf[k]);
            float lo = 0.f, hi = mx + 1e-6f;
#pragma unroll 1
            for (int it = 0; it < 12; ++it) {
                const float thr = 0.5f * (lo + hi);
                unsigned cnt = 0;
#pragma unroll
                for (int k = 0; k < 32; ++k)
                    cnt += (__uint_as_float(u[k]) > thr) ? 1u : 0u;
#pragma unroll
                for (int o = 32; o > 0; o >>= 1) cnt += __shfl_down(cnt, o, 64);
                if ((t & 63) == 0) atomicAdd(&cacc[nextacc + it], cnt);
                LGKM0();
                BAR();
                if (cacc[nextacc + it] >= TOPK) lo = thr; else hi = thr;
            }
            Tf = 0.5f * (lo + hi);
        }

        const float thi = Tf + BAND_M, tlo = Tf - BAND_M;
#pragma unroll
        for (int k = 0; k < 32; ++k) {
            const float a = __uint_as_float(u[k]);
            const int idx = ((k >> 3) * 1024 + t) * 8 + (k & 7);
            if (a > thi) {
                const unsigned s2 = atomicAdd(&scomp[0], 1u);
                sel_idx[r * TOPK + s2] = idx;
                sel_val[r * TOPK + s2] = a;
            } else if (a >= tlo) {
                const unsigned s2 = atomicAdd(&scomp[1], 1u);
                if (s2 < BAND_CAP) band_idx[r * BAND_CAP + s2] = idx;
            }
        }
        LGKM0();
        BAR();
        if (t == 0) {
            cdef[r]  = (int)scomp[0];
            int nb = (int)scomp[1]; if (nb > BAND_CAP) nb = BAND_CAP;
            nband[r] = nb;
            muarr[r] = mu; sinvarr[r] = sinv;
        }
    }
}

// ---------------- K2b: fp64 refinement + final select + feat scatter ------------
__global__ __launch_bounds__(256) void refine_select(
    const float* __restrict__ X, const float* __restrict__ Wenc,
    const float* __restrict__ benc, const float* __restrict__ gamma,
    const float* __restrict__ beta, const int* __restrict__ band_idx,
    const int* __restrict__ cdef, const int* __restrict__ nband,
    const float* __restrict__ muarr, const float* __restrict__ sinvarr,
    int* __restrict__ sel_idx, float* __restrict__ sel_val,
    float* __restrict__ feat)
{
    __shared__ float xs[DIM];
    __shared__ float cval[BAND_CAP];
    __shared__ int   cidx[BAND_CAP];
    __shared__ int   scnt;
    const int t = threadIdx.x;
    const long r = blockIdx.x;
    const int w = t >> 6, l = t & 63;

    for (int i = t; i < DIM; i += 256) xs[i] = X[r * DIM + i];
    if (t == 0) scnt = 0;
    const int nb = nband[r];
    const int cd = cdef[r];
    int need = TOPK - cd; if (need > nb) need = nb;
    const double mu = (double)muarr[r], sinv = (double)sinvarr[r];

    if (feat && t < cd)
        feat[r * (size_t)FDICT + sel_idx[r * TOPK + t]] = sel_val[r * TOPK + t];
    __syncthreads();

    for (int c = w; c < nb; c += 4) {
        const int fi = band_idx[r * BAND_CAP + c];
        const float* wr = Wenc + (size_t)fi * DIM;
        double s = 0.0;
        for (int k = l; k < DIM; k += 64) s = fma((double)xs[k], (double)wr[k], s);
#pragma unroll
        for (int o = 32; o > 0; o >>= 1) s += __shfl_down(s, o, 64);
        if (l == 0) {
            const double z = s + (double)benc[fi];
            const double a = (z - mu) * sinv * (double)gamma[fi] + (double)beta[fi];
            cval[c] = fmaxf((float)a, 0.f);
            cidx[c] = fi;
        }
    }
    __syncthreads();
    if (t < nb) {
        const float v = cval[t];
        const int id = cidx[t];
        int rank = 0;
        for (int j = 0; j < nb; ++j) {
            const float vj = cval[j];
            rank += (vj > v) || (vj == v && cidx[j] < id);
        }
        if (rank < need) {
            const int s = atomicAdd(&scnt, 1);
            sel_idx[r * TOPK + cd + s] = id;
            sel_val[r * TOPK + cd + s] = v;
            if (feat) feat[r * (size_t)FDICT + id] = v;
        }
    }
}

// ---------------- K4: sparse decode (bf16 W_decT, fp32 math) --------------------
__global__ __launch_bounds__(384) void decode(
    const int* __restrict__ sel_idx, const float* __restrict__ sel_val,
    const unsigned short* __restrict__ WdTb, const float* __restrict__ bdec,
    float* __restrict__ out)
{
    __shared__ int   sidx[TOPK];
    __shared__ float sval[TOPK];
    const int t = threadIdx.x;
    const long r = blockIdx.x;
    if (t < TOPK) { sidx[t] = sel_idx[r * TOPK + t]; sval[t] = sel_val[r * TOPK + t]; }
    __syncthreads();
    const float2 b2 = *(const float2*)(bdec + t * 2);
    float a0 = b2.x, a1 = b2.y;
    for (int j = 0; j < TOPK; ++j) {
        const unsigned wp = *(const unsigned*)(WdTb + (size_t)sidx[j] * DIM + t * 2);
        const float v = sval[j];
        a0 = fmaf(v, __uint_as_float((wp & 0xFFFFu) << 16), a0);
        a1 = fmaf(v, __uint_as_float(wp & 0xFFFF0000u), a1);
    }
    float2 o2; o2.x = a0; o2.y = a1;
    *(float2*)(out + r * DIM + t * 2) = o2;
}

// ---------------- K5 (small-ws only): zero rows + scatter ------------------------
__global__ __launch_bounds__(1024) void featfill(
    const int* __restrict__ sel_idx, const float* __restrict__ sel_val,
    float* __restrict__ feat)
{
    const int t = threadIdx.x;
    const long r = blockIdx.x;
    const f32x4 z4 = (f32x4){0.f, 0.f, 0.f, 0.f};
    f32x4* row4 = (f32x4*)(feat + r * FDICT);
    for (int i = t; i < FDICT / 4; i += 1024)
        __builtin_nontemporal_store(z4, &row4[i]);
    __syncthreads();
    if (t < TOPK)
        feat[r * FDICT + sel_idx[r * TOPK + t]] = sel_val[r * TOPK + t];
}

extern "C" void kernel_launch(void* const* d_in, const int* in_sizes, int n_in,
                              void* d_out, int out_size, void* d_ws, size_t ws_size,
                              hipStream_t stream)
{
    const float* x     = (const float*)d_in[0];
    const float* Wenc  = (const float*)d_in[1];
    const float* benc  = (const float*)d_in[2];
    const float* gamma = (const float*)d_in[3];
    const float* beta  = (const float*)d_in[4];
    const float* Wdec  = (const float*)d_in[5];
    const float* bdec  = (const float*)d_in[6];

    float* out  = (float*)d_out;                      // [8192*768] fp32
    float* feat = out + (size_t)R_TOT * DIM;          // [8192*32768] fp32 region

    unsigned short* Xb = (unsigned short*)out;        // dead until decode writes out

    char* ws = (char*)d_ws;
    int*   sidx  = (int*)ws;                                        // 4 MB
    float* sval  = (float*)(ws + (size_t)R_TOT * TOPK * 4);         // 4 MB
    int*   bidx  = (int*)(ws + (size_t)R_TOT * TOPK * 8);           // 6.3 MB
    int*   cdef  = (int*)(ws + (size_t)R_TOT * (TOPK * 8 + BAND_CAP * 4));
    int*   nbnd  = cdef + R_TOT;
    float* muarr = (float*)(nbnd + R_TOT);
    float* sinva = muarr + R_TOT;
    float* gbinfo = sinva + R_TOT;                                  // 8 floats
    int*   flags = (int*)(ws + (15ull << 20));                      // 32 KB

    // big-path buffers
    float2* partials = (float2*)(ws + (16ull << 20));               // 8 MB
    int*    cntg     = (int*)(ws + (24ull << 20));                  // 4 MB
    float2* candv    = (float2*)(ws + (28ull << 20));               // 134 MB

    const size_t WS_NEED = 288ull << 20;
    const bool big = (ws_size >= WS_NEED);

    unsigned short *Zb, *Wb, *WdTb;
    if (big) {
        Zb   = nullptr;                                             // not used
        Wb   = (unsigned short*)(ws + (168ull << 20));              // 48.3 MB
        WdTb = (unsigned short*)(ws + (224ull << 20));              // 48.3 MB
    } else {
        Zb   = (unsigned short*)feat;
        Wb   = (unsigned short*)((char*)feat + 536870912ull);
        WdTb = (unsigned short*)((char*)feat + 587202560ull);
    }
    float* featArg = big ? feat : nullptr;

    prep_fused<<<1536 + 2048 + 24576 + 1, 256, 0, stream>>>(
        x, Wenc, Wdec, gamma, beta, Xb, Wb, WdTb, gbinfo);

    if (big) {
        enc_gemm<<<4096, 512, 0, stream>>>(Xb, Wb, benc, nullptr, feat,
                                           candv, cntg, partials);
        topk_cand<<<R_TOT, 256, 0, stream>>>(partials, cntg, candv, gbinfo,
                                             flags, sidx, sval, bidx, cdef,
                                             nbnd, muarr, sinva);
        topk_fallback<<<R_TOT, 1024, 0, stream>>>(x, Wenc, benc, gamma, beta,
                                                  flags, sidx, sval, bidx,
                                                  cdef, nbnd, muarr, sinva);
        refine_select<<<R_TOT, 256, 0, stream>>>(x, Wenc, benc, gamma, beta,
                                                 bidx, cdef, nbnd, muarr, sinva,
                                                 sidx, sval, feat);
        decode<<<R_TOT, 384, 0, stream>>>(sidx, sval, WdTb, bdec, out);
    } else {
        enc_gemm<<<4096, 512, 0, stream>>>(Xb, Wb, benc, Zb, nullptr,
                                           nullptr, nullptr, nullptr);
        topk_zb<<<R_TOT / 4, 1024, 0, stream>>>(Zb, gamma, beta, gbinfo,
                                                sidx, sval, bidx, cdef, nbnd,
                                                muarr, sinva);
        refine_select<<<R_TOT, 256, 0, stream>>>(x, Wenc, benc, gamma, beta,
                                                 bidx, cdef, nbnd, muarr, sinva,
                                                 sidx, sval, nullptr);
        decode<<<R_TOT, 384, 0, stream>>>(sidx, sval, WdTb, bdec, out);
        featfill<<<R_TOT, 1024, 0, stream>>>(sidx, sval, feat);
    }
}